// Round 12
// baseline (1153.140 us; speedup 1.0000x reference)
//
#include <hip/hip_runtime.h>
#include <hip/hip_bf16.h>
#include <math.h>

#define IGNORE_INDEX (-100)

typedef __attribute__((ext_vector_type(4))) float f32x4;
typedef __attribute__((ext_vector_type(16))) float f32x16;
typedef __attribute__((ext_vector_type(4))) int i32x4;
typedef __attribute__((ext_vector_type(8))) int i32x8;

// Problem sizes (fixed by the reference)
static const int NTOK = 2 * 4096;   // 8192 tokens (GEMM M)
static const int DIM  = 2048;       // embed dim (GEMM K)
static const int VOC  = 32000;      // vocab (GEMM N)
static const int BM = 256, BN = 256;
static const int KS = 64;           // K per slot
static const int NPH = DIM / KS;    // 32 slots
static const int NVT = VOC / BN;    // 125 vocab tiles
static const int MT  = NTOK / BM;   // 32 m tiles
static const float WSCALE = 16.0f;  // W pre-scale (exact power of 2)
#define SCL1 0x7F7F7F7F             // e8m0 scale byte 0x7F = 2^0 = 1.0

// ---------------- helpers ----------------

__device__ inline void gload_lds16(const void* g, void* l) {
  __builtin_amdgcn_global_load_lds(
      (const __attribute__((address_space(1))) void*)g,
      (__attribute__((address_space(3))) void*)l,
      16, 0, 0);
}

// ---------------- kernel 1: fp32 -> fp8 e4m3 cast (with scale) ----------------

__global__ void cast_f32_fp8(const float* __restrict__ in,
                             unsigned char* __restrict__ out, long n8, float scale) {
  long i0 = (long)blockIdx.x * blockDim.x + threadIdx.x;
  long stride = (long)gridDim.x * blockDim.x;
  for (long i = i0; i < n8; i += stride) {
    const float4* p = (const float4*)(in + i * 8);
    float4 a = p[0], b = p[1];
    int lo = __builtin_amdgcn_cvt_pk_fp8_f32(a.x * scale, a.y * scale, 0, false);
    lo = __builtin_amdgcn_cvt_pk_fp8_f32(a.z * scale, a.w * scale, lo, true);
    int hi = __builtin_amdgcn_cvt_pk_fp8_f32(b.x * scale, b.y * scale, 0, false);
    hi = __builtin_amdgcn_cvt_pk_fp8_f32(b.z * scale, b.w * scale, hi, true);
    int2 o; o.x = lo; o.y = hi;
    *(int2*)(out + i * 8) = o;
  }
}

// ---------------- kernel 2: 256x256 MX-fp8 GEMM (32x32x64), ring-2, 2 blocks/CU ----------
// Layout identical to R7/R11 (verified absmax 0.0): fragment-major lane-linear LDS;
// frag f (32 rows x 64 k-bytes, 2KB) at ring*16384 + f*2048, half h at +h*1024 + lane*16.
// R12: ring depth 4 -> 2 (LDS 128KB -> 64KB) => 2 blocks/CU. R6-R11 established the
// slot time is ~4.7-5.1k cyc/CU regardless of intra-block schedule with only the MFMA
// pipe 21% busy — the stall needs a CO-RESIDENT block to fill it (m114 overlap).
// Body: vmcnt(0) [slot n staged] -> barrier -> stage slot n+1 -> reads+MFMA slot n.
// WAR safe: ring-r reads drain (compiler lgkm before last MFMA of body n-1) before
// body n's barrier, which precedes the re-stage of ring r.

#define VM0  asm volatile("s_waitcnt vmcnt(0)" ::: "memory")
#define BARRIER asm volatile("s_barrier" ::: "memory")

#define MS(ACC, AV, BV) \
  ACC = __builtin_amdgcn_mfma_scale_f32_32x32x64_f8f6f4( \
      AV, BV, ACC, 0, 0, 0, SCL1, 0, SCL1)

#define PACK8(LO, HI) {LO[0], LO[1], LO[2], LO[3], HI[0], HI[1], HI[2], HI[3]}

#define STAGE(DST) do { \
  char* _dA = stA + (DST) * 16384; \
  char* _dB = stB + (DST) * 16384; \
  gload_lds16(aS0, _dA); \
  gload_lds16(aS1, _dA + 1024); \
  gload_lds16(bS0, _dB); \
  gload_lds16(bS1, _dB + 1024); \
  aS0 += KS; aS1 += KS; bS0 += KS; bS1 += KS; \
} while (0)

// read slot (RING) into the single named register set, then pack + 8 MFMA
#define SLOT_COMPUTE(RING) do { \
  const char* _Ab = aRd + (RING) * 16384; \
  const char* _Bb = bRd + (RING) * 16384; \
  i32x4 qb0l = *(const i32x4*)(_Bb);        i32x4 qb0h = *(const i32x4*)(_Bb + 1024); \
  i32x4 qa0l = *(const i32x4*)(_Ab);        i32x4 qa0h = *(const i32x4*)(_Ab + 1024); \
  i32x4 qb1l = *(const i32x4*)(_Bb + 2048); i32x4 qb1h = *(const i32x4*)(_Bb + 3072); \
  i32x4 qa1l = *(const i32x4*)(_Ab + 2048); i32x4 qa1h = *(const i32x4*)(_Ab + 3072); \
  i32x4 qa2l = *(const i32x4*)(_Ab + 4096); i32x4 qa2h = *(const i32x4*)(_Ab + 5120); \
  i32x4 qa3l = *(const i32x4*)(_Ab + 6144); i32x4 qa3h = *(const i32x4*)(_Ab + 7168); \
  i32x8 _B0 = PACK8(qb0l, qb0h); \
  i32x8 _A0 = PACK8(qa0l, qa0h); \
  i32x8 _B1 = PACK8(qb1l, qb1h); \
  i32x8 _A1 = PACK8(qa1l, qa1h); \
  __builtin_amdgcn_s_setprio(1); \
  MS(acc[0][0], _A0, _B0); MS(acc[0][1], _A0, _B1); \
  MS(acc[1][0], _A1, _B0); MS(acc[1][1], _A1, _B1); \
  { \
    i32x8 _A2 = PACK8(qa2l, qa2h); \
    i32x8 _A3 = PACK8(qa3l, qa3h); \
    MS(acc[2][0], _A2, _B0); MS(acc[2][1], _A2, _B1); \
    MS(acc[3][0], _A3, _B0); MS(acc[3][1], _A3, _B1); \
  } \
  __builtin_amdgcn_s_setprio(0); \
} while (0)

__launch_bounds__(512, 2)
__global__ void lce_gemm(const unsigned char* __restrict__ xq,
                         const unsigned char* __restrict__ wq,
                         float* __restrict__ pmax, float* __restrict__ psum) {
  extern __shared__ char smem[];
  char* smA = smem;                    // 2 ring slots x 16 KB
  char* smB = smem + 32768;            // 2 ring slots x 16 KB

  // XCD-aware swizzle (nwg = 4000, divisible by 8), mt-minor
  const int nwg = NVT * MT;            // 4000
  const int cpx = nwg >> 3;            // 500
  const int bid = blockIdx.x;
  const int swz = (bid & 7) * cpx + (bid >> 3);
  const int vt = swz / MT;
  const int mt = swz % MT;
  const int m0 = mt * BM;
  const int v0 = vt * BN;

  const int tid = threadIdx.x;
  const int lane = tid & 63;
  const int w = tid >> 6;              // 0..7
  const int wr = w >> 2, wc = w & 3;   // 2 x 4 wave grid; wave tile 128x64
  const int lc = lane & 31;
  const int lh = lane >> 5;

  f32x16 acc[4][2];
#pragma unroll
  for (int i = 0; i < 4; ++i)
#pragma unroll
    for (int j = 0; j < 2; ++j)
#pragma unroll
      for (int r = 0; r < 16; ++r) acc[i][j][r] = 0.f;

  // ---- staging sources (per-lane global; wave w owns A frag w + B frag w) ----
  const unsigned char* aS0 = xq + (long)(m0 + w * 32 + lc) * DIM + lh * 32;
  const unsigned char* aS1 = aS0 + 16;
  const unsigned char* bS0 = wq + (long)(v0 + w * 32 + lc) * DIM + lh * 32;
  const unsigned char* bS1 = bS0 + 16;
  char* stA = smA + w * 2048;
  char* stB = smB + w * 2048;

  // ---- ds_read bases (lane-linear) ----
  const char* aRd = smA + wr * 4 * 2048 + lane * 16;
  const char* bRd = smB + wc * 2 * 2048 + lane * 16;

  // ---- prologue: stage slot 0 into ring 0 ----
  STAGE(0);

  // ---- main loop: ring-2; stage n+1 after the barrier, compute n ----
#pragma unroll 1
  for (int n = 0; n < NPH; ++n) {
    VM0;                               // slot n's 4 staged loads (per-wave) complete
    BARRIER;                           // all waves' slot-n loads visible; ring slot
                                       // (n+1)&1 reads (body n-1) drained pre-barrier
    if (n < NPH - 1) STAGE((n + 1) & 1);
    SLOT_COMPUTE(n & 1);
  }

  // ---- epilogue: per-row max & sum(exp) over this tile's 256 cols; logits = acc/WSCALE ----
  // 32x32 C/D layout (verified m74/m101): col = lane&31, row = (r&3) + 8*(r>>2) + 4*(lane>>5)
  const float sc = 1.0f / WSCALE;
  float* sm_m = (float*)smem;          // [4][256]
  float* sm_s = (float*)(smem + 4096); // [4][256]
  __syncthreads();                     // loop fully drained; safe to reuse LDS
#pragma unroll
  for (int i = 0; i < 4; ++i) {
#pragma unroll
    for (int r = 0; r < 16; ++r) {
      float l0 = acc[i][0][r] * sc, l1 = acc[i][1][r] * sc;
      float m = fmaxf(l0, l1);
#pragma unroll
      for (int mk = 1; mk < 32; mk <<= 1) m = fmaxf(m, __shfl_xor(m, mk));
      float s = __expf(l0 - m) + __expf(l1 - m);
#pragma unroll
      for (int mk = 1; mk < 32; mk <<= 1) s += __shfl_xor(s, mk);
      if (lc == 0) {
        int R = wr * 128 + i * 32 + (r & 3) + 8 * (r >> 2) + 4 * lh;
        sm_m[wc * 256 + R] = m;
        sm_s[wc * 256 + R] = s;
      }
    }
  }
  __syncthreads();
  if (tid < BM) {
    float ma = sm_m[tid], mb = sm_m[256 + tid], mc = sm_m[512 + tid], md = sm_m[768 + tid];
    float gm = fmaxf(fmaxf(ma, mb), fmaxf(mc, md));
    float gs = sm_s[tid] * __expf(ma - gm) + sm_s[256 + tid] * __expf(mb - gm) +
               sm_s[512 + tid] * __expf(mc - gm) + sm_s[768 + tid] * __expf(md - gm);
    long row = (long)(m0 + tid);
    pmax[row * NVT + vt] = gm;
    psum[row * NVT + vt] = gs;
  }
}

// ---------------- kernel 3: per-token LSE combine + exact fp32 target dot ----------------

__global__ void token_reduce(const float* __restrict__ x, const float* __restrict__ wgt,
                             const int* __restrict__ tgt,
                             const float* __restrict__ pmax, const float* __restrict__ psum,
                             float* __restrict__ nll, float* __restrict__ validf) {
  const int n = blockIdx.x;
  const int tid = threadIdx.x;
  const int lane = tid & 63;
  const int w = tid >> 6;
  __shared__ float smr[4];

  const int t = tgt[n];
  const bool valid = (t != IGNORE_INDEX);
  const int ts = valid ? t : 0;

  // exact fp32 target logit
  const float4* xr = (const float4*)(x + (long)n * DIM);
  const float4* wr = (const float4*)(wgt + (long)ts * DIM);
  float d = 0.f;
  for (int i = tid; i < DIM / 4; i += blockDim.x) {
    float4 a = xr[i], b = wr[i];
    d += a.x * b.x + a.y * b.y + a.z * b.z + a.w * b.w;
  }

  // LSE over 125 partials
  float m = (tid < NVT) ? pmax[(long)n * NVT + tid] : -INFINITY;
  float t1 = m;
#pragma unroll
  for (int mk = 1; mk < 64; mk <<= 1) t1 = fmaxf(t1, __shfl_xor(t1, mk));
  if (lane == 0) smr[w] = t1;
  __syncthreads();
  const float gm = fmaxf(fmaxf(smr[0], smr[1]), fmaxf(smr[2], smr[3]));
  __syncthreads();

  float se = (tid < NVT) ? psum[(long)n * NVT + tid] * __expf(m - gm) : 0.f;
#pragma unroll
  for (int mk = 1; mk < 64; mk <<= 1) se += __shfl_xor(se, mk);
  if (lane == 0) smr[w] = se;
  __syncthreads();
  const float gs = smr[0] + smr[1] + smr[2] + smr[3];
  __syncthreads();

#pragma unroll
  for (int mk = 1; mk < 64; mk <<= 1) d += __shfl_xor(d, mk);
  if (lane == 0) smr[w] = d;
  __syncthreads();
  const float gd = smr[0] + smr[1] + smr[2] + smr[3];

  if (tid == 0) {
    nll[n] = valid ? (gm + logf(gs) - gd) : 0.f;
    validf[n] = valid ? 1.f : 0.f;
  }
}

// ---------------- kernel 4: deterministic final mean ----------------

__global__ void final_reduce(const float* __restrict__ nll, const float* __restrict__ validf,
                             float* __restrict__ out, int n) {
  const int tid = threadIdx.x;
  const int lane = tid & 63;
  const int w = tid >> 6;
  __shared__ float sm1[4], sm2[4];
  float s = 0.f, c = 0.f;
  for (int i = tid; i < n; i += blockDim.x) { s += nll[i]; c += validf[i]; }
#pragma unroll
  for (int mk = 1; mk < 64; mk <<= 1) { s += __shfl_xor(s, mk); c += __shfl_xor(c, mk); }
  if (lane == 0) { sm1[w] = s; sm2[w] = c; }
  __syncthreads();
  if (tid == 0) {
    float ts = sm1[0] + sm1[1] + sm1[2] + sm1[3];
    float tc = sm2[0] + sm2[1] + sm2[2] + sm2[3];
    out[0] = ts / fmaxf(tc, 1.0f);
  }
}

// ---------------- launch ----------------

extern "C" void kernel_launch(void* const* d_in, const int* in_sizes, int n_in,
                              void* d_out, int out_size, void* d_ws, size_t ws_size,
                              hipStream_t stream) {
  const float* x = (const float*)d_in[0];     // [8192, 2048] fp32
  const float* wgt = (const float*)d_in[1];   // [32000, 2048] fp32
  const int* tgt = (const int*)d_in[2];       // [8192] int
  float* out = (float*)d_out;

  char* ws = (char*)d_ws;
  const size_t xq_off = 0;
  const size_t wq_off = (size_t)NTOK * DIM;                        // 16,777,216
  const size_t pm_off = wq_off + (size_t)VOC * DIM;                // 82,313,216
  const size_t ps_off = pm_off + (size_t)NTOK * NVT * 4;
  const size_t nl_off = ps_off + (size_t)NTOK * NVT * 4;
  const size_t vf_off = nl_off + (size_t)NTOK * 4;
  const size_t needed = vf_off + (size_t)NTOK * 4;
  if (ws_size < needed) return;  // workspace too small: fail visibly

  unsigned char* xq = (unsigned char*)(ws + xq_off);
  unsigned char* wq = (unsigned char*)(ws + wq_off);
  float* pmax = (float*)(ws + pm_off);
  float* psum = (float*)(ws + ps_off);
  float* nllv = (float*)(ws + nl_off);
  float* vldf = (float*)(ws + vf_off);

  cast_f32_fp8<<<2048, 256, 0, stream>>>(x, xq, (long)NTOK * DIM / 8, 1.0f);
  cast_f32_fp8<<<4096, 256, 0, stream>>>(wgt, wq, (long)VOC * DIM / 8, WSCALE);

  (void)hipFuncSetAttribute((const void*)lce_gemm,
                            hipFuncAttributeMaxDynamicSharedMemorySize, 65536);
  lce_gemm<<<NVT * MT, 512, 65536, stream>>>(xq, wq, pmax, psum);

  token_reduce<<<NTOK, 256, 0, stream>>>(x, wgt, tgt, pmax, psum, nllv, vldf);
  final_reduce<<<1, 256, 0, stream>>>(nllv, vldf, out, NTOK);
}

// Round 13
// 1105.839 us; speedup vs baseline: 1.0428x; 1.0428x over previous
//
#include <hip/hip_runtime.h>
#include <hip/hip_bf16.h>
#include <math.h>

#define IGNORE_INDEX (-100)

typedef __attribute__((ext_vector_type(4))) float f32x4;
typedef __attribute__((ext_vector_type(16))) float f32x16;
typedef __attribute__((ext_vector_type(4))) int i32x4;
typedef __attribute__((ext_vector_type(8))) int i32x8;

// Problem sizes (fixed by the reference)
static const int NTOK = 2 * 4096;   // 8192 tokens (GEMM M)
static const int DIM  = 2048;       // embed dim (GEMM K)
static const int VOC  = 32000;      // vocab (GEMM N)
static const int BM = 128, BN = 128;
static const int KS = 64;           // K per slot
static const int NPH = DIM / KS;    // 32 slots
static const int NVT = VOC / BN;    // 250 vocab tiles
static const int MT  = NTOK / BM;   // 64 m tiles
static const float WSCALE = 16.0f;  // W pre-scale (exact power of 2)
#define SCL1 0x7F7F7F7F             // e8m0 scale byte 0x7F = 2^0 = 1.0

// ---------------- helpers ----------------

__device__ inline void gload_lds16(const void* g, void* l) {
  __builtin_amdgcn_global_load_lds(
      (const __attribute__((address_space(1))) void*)g,
      (__attribute__((address_space(3))) void*)l,
      16, 0, 0);
}

// ---------------- kernel 1: fp32 -> fp8 e4m3 cast (with scale) ----------------

__global__ void cast_f32_fp8(const float* __restrict__ in,
                             unsigned char* __restrict__ out, long n8, float scale) {
  long i0 = (long)blockIdx.x * blockDim.x + threadIdx.x;
  long stride = (long)gridDim.x * blockDim.x;
  for (long i = i0; i < n8; i += stride) {
    const float4* p = (const float4*)(in + i * 8);
    float4 a = p[0], b = p[1];
    int lo = __builtin_amdgcn_cvt_pk_fp8_f32(a.x * scale, a.y * scale, 0, false);
    lo = __builtin_amdgcn_cvt_pk_fp8_f32(a.z * scale, a.w * scale, lo, true);
    int hi = __builtin_amdgcn_cvt_pk_fp8_f32(b.x * scale, b.y * scale, 0, false);
    hi = __builtin_amdgcn_cvt_pk_fp8_f32(b.z * scale, b.w * scale, hi, true);
    int2 o; o.x = lo; o.y = hi;
    *(int2*)(out + i * 8) = o;
  }
}

// ---------------- kernel 2: 128x128 MX-fp8 GEMM (32x32x64), 4 waves, 4 blocks/CU ----------
// R13: occupancy experiment. R6-R12 pinned at ~1000-1100 TF with 8 waves/CU (228 regs/wave:
// acc 128 + operands). Shrink tile to 128x128 / 4 waves: acc f32x16[2][2] = 64 regs,
// total ~116 < 128 => 4 waves/SIMD (m69 cliff) = 16 waves/CU = 4 independent blocks.
// Same verified MX math/layout (absmax 0.0 in R7-R12): fragment-major lane-linear LDS;
// frag f (32 rows x 64 k-bytes, 2KB) at ring*8192 + f*2048, half h at +h*1024 + lane*16.
// Ring-2 (32 KB LDS). Body: vmcnt(0) -> barrier -> stage slot n+1 -> reads+MFMA slot n.
// WAR safe: all 8 reads feed the MFMAs (compiler lgkm), so each wave's reads complete
// before it reaches the next barrier, which precedes the re-stage of that ring slot.

#define VM0  asm volatile("s_waitcnt vmcnt(0)" ::: "memory")
#define BARRIER asm volatile("s_barrier" ::: "memory")

#define MS(ACC, AV, BV) \
  ACC = __builtin_amdgcn_mfma_scale_f32_32x32x64_f8f6f4( \
      AV, BV, ACC, 0, 0, 0, SCL1, 0, SCL1)

#define PACK8(LO, HI) {LO[0], LO[1], LO[2], LO[3], HI[0], HI[1], HI[2], HI[3]}

#define STAGE(DST) do { \
  char* _dA = stA + (DST) * 8192; \
  char* _dB = stB + (DST) * 8192; \
  gload_lds16(aS0, _dA); \
  gload_lds16(aS1, _dA + 1024); \
  gload_lds16(bS0, _dB); \
  gload_lds16(bS1, _dB + 1024); \
  aS0 += KS; aS1 += KS; bS0 += KS; bS1 += KS; \
} while (0)

// read slot (RING) operands (named, never address-taken), pack + 4 MFMA
#define SLOT_COMPUTE(RING) do { \
  const char* _Ab = aRd + (RING) * 8192; \
  const char* _Bb = bRd + (RING) * 8192; \
  i32x4 qb0l = *(const i32x4*)(_Bb);        i32x4 qb0h = *(const i32x4*)(_Bb + 1024); \
  i32x4 qa0l = *(const i32x4*)(_Ab);        i32x4 qa0h = *(const i32x4*)(_Ab + 1024); \
  i32x4 qb1l = *(const i32x4*)(_Bb + 2048); i32x4 qb1h = *(const i32x4*)(_Bb + 3072); \
  i32x4 qa1l = *(const i32x4*)(_Ab + 2048); i32x4 qa1h = *(const i32x4*)(_Ab + 3072); \
  i32x8 _B0 = PACK8(qb0l, qb0h); \
  i32x8 _A0 = PACK8(qa0l, qa0h); \
  i32x8 _B1 = PACK8(qb1l, qb1h); \
  i32x8 _A1 = PACK8(qa1l, qa1h); \
  __builtin_amdgcn_s_setprio(1); \
  MS(acc[0][0], _A0, _B0); MS(acc[0][1], _A0, _B1); \
  MS(acc[1][0], _A1, _B0); MS(acc[1][1], _A1, _B1); \
  __builtin_amdgcn_s_setprio(0); \
} while (0)

__launch_bounds__(256, 4)
__global__ void lce_gemm(const unsigned char* __restrict__ xq,
                         const unsigned char* __restrict__ wq,
                         float* __restrict__ pmax, float* __restrict__ psum) {
  extern __shared__ char smem[];
  char* smA = smem;                    // 2 ring slots x 8 KB
  char* smB = smem + 16384;            // 2 ring slots x 8 KB

  // XCD-aware swizzle (nwg = 16000, divisible by 8), mt-minor for W-panel L2 reuse
  const int nwg = NVT * MT;            // 16000
  const int cpx = nwg >> 3;            // 2000
  const int bid = blockIdx.x;
  const int swz = (bid & 7) * cpx + (bid >> 3);
  const int vt = swz / MT;
  const int mt = swz % MT;
  const int m0 = mt * BM;
  const int v0 = vt * BN;

  const int tid = threadIdx.x;
  const int lane = tid & 63;
  const int w = tid >> 6;              // 0..3
  const int wr = w >> 1, wc = w & 1;   // 2 x 2 wave grid; wave tile 64x64
  const int lc = lane & 31;
  const int lh = lane >> 5;

  f32x16 acc[2][2];
#pragma unroll
  for (int i = 0; i < 2; ++i)
#pragma unroll
    for (int j = 0; j < 2; ++j)
#pragma unroll
      for (int r = 0; r < 16; ++r) acc[i][j][r] = 0.f;

  // ---- staging sources (per-lane global; wave w owns A frag w + B frag w) ----
  const unsigned char* aS0 = xq + (long)(m0 + w * 32 + lc) * DIM + lh * 32;
  const unsigned char* aS1 = aS0 + 16;
  const unsigned char* bS0 = wq + (long)(v0 + w * 32 + lc) * DIM + lh * 32;
  const unsigned char* bS1 = bS0 + 16;
  char* stA = smA + w * 2048;          // frag w base; halves at +0 / +1024
  char* stB = smB + w * 2048;

  // ---- ds_read bases (lane-linear): wave reads A frags {2wr,2wr+1}, B frags {2wc,2wc+1}
  const char* aRd = smA + wr * 4096 + lane * 16;
  const char* bRd = smB + wc * 4096 + lane * 16;

  // ---- prologue: stage slot 0 into ring 0 ----
  STAGE(0);

  // ---- main loop: ring-2; stage n+1 after the barrier, compute n ----
#pragma unroll 1
  for (int n = 0; n < NPH; ++n) {
    VM0;                               // own slot-n loads complete
    BARRIER;                           // all waves' slot-n loads visible
    if (n < NPH - 1) STAGE((n + 1) & 1);
    SLOT_COMPUTE(n & 1);
  }

  // ---- epilogue: per-row max & sum(exp) over this tile's 128 cols; logits = acc/WSCALE ----
  // 32x32 C/D layout (verified m74/m101): col = lane&31, row = (r&3) + 8*(r>>2) + 4*(lane>>5)
  const float sc = 1.0f / WSCALE;
  float* sm_m = (float*)smem;          // [2][128]
  float* sm_s = (float*)(smem + 1024); // [2][128]
  __syncthreads();                     // loop fully drained; safe to reuse LDS
#pragma unroll
  for (int i = 0; i < 2; ++i) {
#pragma unroll
    for (int r = 0; r < 16; ++r) {
      float l0 = acc[i][0][r] * sc, l1 = acc[i][1][r] * sc;
      float m = fmaxf(l0, l1);
#pragma unroll
      for (int mk = 1; mk < 32; mk <<= 1) m = fmaxf(m, __shfl_xor(m, mk));
      float s = __expf(l0 - m) + __expf(l1 - m);
#pragma unroll
      for (int mk = 1; mk < 32; mk <<= 1) s += __shfl_xor(s, mk);
      if (lc == 0) {
        int R = wr * 64 + i * 32 + (r & 3) + 8 * (r >> 2) + 4 * lh;
        sm_m[wc * 128 + R] = m;
        sm_s[wc * 128 + R] = s;
      }
    }
  }
  __syncthreads();
  if (tid < BM) {
    float ma = sm_m[tid], mb = sm_m[128 + tid];
    float gm = fmaxf(ma, mb);
    float gs = sm_s[tid] * __expf(ma - gm) + sm_s[128 + tid] * __expf(mb - gm);
    long row = (long)(m0 + tid);
    pmax[row * NVT + vt] = gm;
    psum[row * NVT + vt] = gs;
  }
}

// ---------------- kernel 3: per-token LSE combine + exact fp32 target dot ----------------

__global__ void token_reduce(const float* __restrict__ x, const float* __restrict__ wgt,
                             const int* __restrict__ tgt,
                             const float* __restrict__ pmax, const float* __restrict__ psum,
                             float* __restrict__ nll, float* __restrict__ validf) {
  const int n = blockIdx.x;
  const int tid = threadIdx.x;
  const int lane = tid & 63;
  const int w = tid >> 6;
  __shared__ float smr[4];

  const int t = tgt[n];
  const bool valid = (t != IGNORE_INDEX);
  const int ts = valid ? t : 0;

  // exact fp32 target logit
  const float4* xr = (const float4*)(x + (long)n * DIM);
  const float4* wr = (const float4*)(wgt + (long)ts * DIM);
  float d = 0.f;
  for (int i = tid; i < DIM / 4; i += blockDim.x) {
    float4 a = xr[i], b = wr[i];
    d += a.x * b.x + a.y * b.y + a.z * b.z + a.w * b.w;
  }

  // LSE over 250 partials
  float m = (tid < NVT) ? pmax[(long)n * NVT + tid] : -INFINITY;
  float t1 = m;
#pragma unroll
  for (int mk = 1; mk < 64; mk <<= 1) t1 = fmaxf(t1, __shfl_xor(t1, mk));
  if (lane == 0) smr[w] = t1;
  __syncthreads();
  const float gm = fmaxf(fmaxf(smr[0], smr[1]), fmaxf(smr[2], smr[3]));
  __syncthreads();

  float se = (tid < NVT) ? psum[(long)n * NVT + tid] * __expf(m - gm) : 0.f;
#pragma unroll
  for (int mk = 1; mk < 64; mk <<= 1) se += __shfl_xor(se, mk);
  if (lane == 0) smr[w] = se;
  __syncthreads();
  const float gs = smr[0] + smr[1] + smr[2] + smr[3];
  __syncthreads();

#pragma unroll
  for (int mk = 1; mk < 64; mk <<= 1) d += __shfl_xor(d, mk);
  if (lane == 0) smr[w] = d;
  __syncthreads();
  const float gd = smr[0] + smr[1] + smr[2] + smr[3];

  if (tid == 0) {
    nll[n] = valid ? (gm + logf(gs) - gd) : 0.f;
    validf[n] = valid ? 1.f : 0.f;
  }
}

// ---------------- kernel 4: deterministic final mean ----------------

__global__ void final_reduce(const float* __restrict__ nll, const float* __restrict__ validf,
                             float* __restrict__ out, int n) {
  const int tid = threadIdx.x;
  const int lane = tid & 63;
  const int w = tid >> 6;
  __shared__ float sm1[4], sm2[4];
  float s = 0.f, c = 0.f;
  for (int i = tid; i < n; i += blockDim.x) { s += nll[i]; c += validf[i]; }
#pragma unroll
  for (int mk = 1; mk < 64; mk <<= 1) { s += __shfl_xor(s, mk); c += __shfl_xor(c, mk); }
  if (lane == 0) { sm1[w] = s; sm2[w] = c; }
  __syncthreads();
  if (tid == 0) {
    float ts = sm1[0] + sm1[1] + sm1[2] + sm1[3];
    float tc = sm2[0] + sm2[1] + sm2[2] + sm2[3];
    out[0] = ts / fmaxf(tc, 1.0f);
  }
}

// ---------------- launch ----------------

extern "C" void kernel_launch(void* const* d_in, const int* in_sizes, int n_in,
                              void* d_out, int out_size, void* d_ws, size_t ws_size,
                              hipStream_t stream) {
  const float* x = (const float*)d_in[0];     // [8192, 2048] fp32
  const float* wgt = (const float*)d_in[1];   // [32000, 2048] fp32
  const int* tgt = (const int*)d_in[2];       // [8192] int
  float* out = (float*)d_out;

  char* ws = (char*)d_ws;
  const size_t xq_off = 0;
  const size_t wq_off = (size_t)NTOK * DIM;                        // 16,777,216
  const size_t pm_off = wq_off + (size_t)VOC * DIM;                // 82,313,216
  const size_t ps_off = pm_off + (size_t)NTOK * NVT * 4;
  const size_t nl_off = ps_off + (size_t)NTOK * NVT * 4;
  const size_t vf_off = nl_off + (size_t)NTOK * 4;
  const size_t needed = vf_off + (size_t)NTOK * 4;
  if (ws_size < needed) return;  // workspace too small: fail visibly

  unsigned char* xq = (unsigned char*)(ws + xq_off);
  unsigned char* wq = (unsigned char*)(ws + wq_off);
  float* pmax = (float*)(ws + pm_off);
  float* psum = (float*)(ws + ps_off);
  float* nllv = (float*)(ws + nl_off);
  float* vldf = (float*)(ws + vf_off);

  cast_f32_fp8<<<2048, 256, 0, stream>>>(x, xq, (long)NTOK * DIM / 8, 1.0f);
  cast_f32_fp8<<<4096, 256, 0, stream>>>(wgt, wq, (long)VOC * DIM / 8, WSCALE);

  (void)hipFuncSetAttribute((const void*)lce_gemm,
                            hipFuncAttributeMaxDynamicSharedMemorySize, 32768);
  lce_gemm<<<NVT * MT, 256, 32768, stream>>>(xq, wq, pmax, psum);

  token_reduce<<<NTOK, 256, 0, stream>>>(x, wgt, tgt, pmax, psum, nllv, vldf);
  final_reduce<<<1, 256, 0, stream>>>(nllv, vldf, out, NTOK);
}

// Round 14
// 1032.052 us; speedup vs baseline: 1.1173x; 1.0715x over previous
//
#include <hip/hip_runtime.h>
#include <hip/hip_bf16.h>
#include <math.h>

#define IGNORE_INDEX (-100)

typedef __attribute__((ext_vector_type(4))) float f32x4;
typedef __attribute__((ext_vector_type(4))) int i32x4;
typedef __attribute__((ext_vector_type(8))) int i32x8;

// Problem sizes (fixed by the reference)
static const int NTOK = 2 * 4096;   // 8192 tokens (GEMM M)
static const int DIM  = 2048;       // embed dim (GEMM K)
static const int VOC  = 32000;      // vocab (GEMM N)
static const int BM = 128, BN = 128;
static const int BKB = 128;         // K bytes per step (fp8)
static const int NKS = DIM / BKB;   // 16 K-steps
static const int NVT = VOC / BN;    // 250 vocab tiles
static const int MT  = NTOK / BM;   // 64 m tiles
static const float WSCALE = 16.0f;  // W pre-scale (exact power of 2)
#define SCL1 0x7F7F7F7F             // e8m0 scale byte 0x7F = 2^0 = 1.0

// ---------------- helpers ----------------

__device__ inline void gload_lds16(const void* g, void* l) {
  __builtin_amdgcn_global_load_lds(
      (const __attribute__((address_space(1))) void*)g,
      (__attribute__((address_space(3))) void*)l,
      16, 0, 0);
}

// ---------------- kernel 1: fp32 -> fp8 e4m3 cast (with scale) ----------------

__global__ void cast_f32_fp8(const float* __restrict__ in,
                             unsigned char* __restrict__ out, long n8, float scale) {
  long i0 = (long)blockIdx.x * blockDim.x + threadIdx.x;
  long stride = (long)gridDim.x * blockDim.x;
  for (long i = i0; i < n8; i += stride) {
    const float4* p = (const float4*)(in + i * 8);
    float4 a = p[0], b = p[1];
    int lo = __builtin_amdgcn_cvt_pk_fp8_f32(a.x * scale, a.y * scale, 0, false);
    lo = __builtin_amdgcn_cvt_pk_fp8_f32(a.z * scale, a.w * scale, lo, true);
    int hi = __builtin_amdgcn_cvt_pk_fp8_f32(b.x * scale, b.y * scale, 0, false);
    hi = __builtin_amdgcn_cvt_pk_fp8_f32(b.z * scale, b.w * scale, hi, true);
    int2 o; o.x = lo; o.y = hi;
    *(int2*)(out + i * 8) = o;
  }
}

// ---------------- kernel 2: m148-replica — 128x128 MX-fp8 GEMM, 16x16x128, K=128 ----
// m97/m148 structure (learn_hip ladder, 1628 TF @4k for MX-fp8 K=128): 4 waves,
// SINGLE-buffered static LDS (32 KB), plain __syncthreads(), compiler-scheduled
// waitcnts, no setprio, no inline-asm barriers.
// LDS layout (fragment-major, lane-linear; generalizes R6-R13's verified pattern):
//   frag f = 16 rows x 128 k-bytes (2 KB) at f*2048; unit u in {0,1}: u*1024 + lane*16.
//   lane l <-> global (row f*16 + (l&15), k-bytes (l>>4)*32 + u*16): each lane's two
//   16B units are its CONTIGUOUS 32-byte 16x16x128 MFMA operand slice.
// Both gload_lds (linear dest) and ds_read_b128 (base + lane*16) are lane-linear
// => zero bank conflicts by construction (measured 0 across R6-R13).

#define MS4(ACC, AV, BV) \
  ACC = __builtin_amdgcn_mfma_scale_f32_16x16x128_f8f6f4( \
      AV, BV, ACC, 0, 0, 0, SCL1, 0, SCL1)

#define PACK8(LO, HI) {LO[0], LO[1], LO[2], LO[3], HI[0], HI[1], HI[2], HI[3]}

__launch_bounds__(256)
__global__ void lce_gemm(const unsigned char* __restrict__ xq,
                         const unsigned char* __restrict__ wq,
                         float* __restrict__ pmax, float* __restrict__ psum) {
  __shared__ __align__(16) char smA[16384];   // 8 frags x 2 KB
  __shared__ __align__(16) char smB[16384];

  // XCD-aware swizzle (nwg = 16000, divisible by 8), mt-minor for W-panel L2 reuse
  const int nwg = NVT * MT;            // 16000
  const int cpx = nwg >> 3;            // 2000
  const int bid = blockIdx.x;
  const int swz = (bid & 7) * cpx + (bid >> 3);
  const int vt = swz / MT;
  const int mt = swz % MT;
  const int m0 = mt * BM;
  const int v0 = vt * BN;

  const int tid = threadIdx.x;
  const int lane = tid & 63;
  const int w = tid >> 6;              // 0..3
  const int wr = w >> 1, wc = w & 1;   // 2 x 2 wave grid; wave tile 64x64
  const int li = lane & 15, lg = lane >> 4;

  f32x4 acc[4][4];
  const f32x4 z = {0.f, 0.f, 0.f, 0.f};
#pragma unroll
  for (int i = 0; i < 4; ++i)
#pragma unroll
    for (int j = 0; j < 4; ++j) acc[i][j] = z;

  // ---- staging: wave w owns frags {2w, 2w+1} of A and of B ----
  // per-lane source: row = base + frag*16 + li, k-bytes = ks*128 + lg*32 (+16 for unit 1)
  const unsigned char* aP0 = xq + (long)(m0 + 2 * w * 16 + li) * DIM + lg * 32;
  const unsigned char* aP1 = xq + (long)(m0 + (2 * w + 1) * 16 + li) * DIM + lg * 32;
  const unsigned char* bP0 = wq + (long)(v0 + 2 * w * 16 + li) * DIM + lg * 32;
  const unsigned char* bP1 = wq + (long)(v0 + (2 * w + 1) * 16 + li) * DIM + lg * 32;
  char* dA0 = smA + 2 * w * 2048;
  char* dA1 = smA + (2 * w + 1) * 2048;
  char* dB0 = smB + 2 * w * 2048;
  char* dB1 = smB + (2 * w + 1) * 2048;

  // ---- ds_read bases (lane-linear): wave reads A frags wr*4+i, B frags wc*4+j ----
  const char* aRd = smA + wr * 4 * 2048 + lane * 16;
  const char* bRd = smB + wc * 4 * 2048 + lane * 16;

  // ---- main loop: 16 K-steps, single-buffered, compiler-scheduled ----
#pragma unroll 1
  for (int ks = 0; ks < NKS; ++ks) {
    __syncthreads();   // previous step's ds_reads done before overwrite
    gload_lds16(aP0, dA0);      gload_lds16(aP0 + 16, dA0 + 1024);
    gload_lds16(aP1, dA1);      gload_lds16(aP1 + 16, dA1 + 1024);
    gload_lds16(bP0, dB0);      gload_lds16(bP0 + 16, dB0 + 1024);
    gload_lds16(bP1, dB1);      gload_lds16(bP1 + 16, dB1 + 1024);
    aP0 += BKB; aP1 += BKB; bP0 += BKB; bP1 += BKB;
    __syncthreads();   // staged data visible (compiler drains vmcnt)

    i32x4 a0l = *(const i32x4*)(aRd);        i32x4 a0h = *(const i32x4*)(aRd + 1024);
    i32x4 a1l = *(const i32x4*)(aRd + 2048); i32x4 a1h = *(const i32x4*)(aRd + 3072);
    i32x4 a2l = *(const i32x4*)(aRd + 4096); i32x4 a2h = *(const i32x4*)(aRd + 5120);
    i32x4 a3l = *(const i32x4*)(aRd + 6144); i32x4 a3h = *(const i32x4*)(aRd + 7168);
    i32x4 b0l = *(const i32x4*)(bRd);        i32x4 b0h = *(const i32x4*)(bRd + 1024);
    i32x4 b1l = *(const i32x4*)(bRd + 2048); i32x4 b1h = *(const i32x4*)(bRd + 3072);
    i32x4 b2l = *(const i32x4*)(bRd + 4096); i32x4 b2h = *(const i32x4*)(bRd + 5120);
    i32x4 b3l = *(const i32x4*)(bRd + 6144); i32x4 b3h = *(const i32x4*)(bRd + 7168);

    i32x8 A0 = PACK8(a0l, a0h);
    i32x8 A1 = PACK8(a1l, a1h);
    i32x8 A2 = PACK8(a2l, a2h);
    i32x8 A3 = PACK8(a3l, a3h);
    i32x8 B0 = PACK8(b0l, b0h);
    i32x8 B1 = PACK8(b1l, b1h);
    i32x8 B2 = PACK8(b2l, b2h);
    i32x8 B3 = PACK8(b3l, b3h);

    MS4(acc[0][0], A0, B0); MS4(acc[0][1], A0, B1);
    MS4(acc[0][2], A0, B2); MS4(acc[0][3], A0, B3);
    MS4(acc[1][0], A1, B0); MS4(acc[1][1], A1, B1);
    MS4(acc[1][2], A1, B2); MS4(acc[1][3], A1, B3);
    MS4(acc[2][0], A2, B0); MS4(acc[2][1], A2, B1);
    MS4(acc[2][2], A2, B2); MS4(acc[2][3], A2, B3);
    MS4(acc[3][0], A3, B0); MS4(acc[3][1], A3, B1);
    MS4(acc[3][2], A3, B2); MS4(acc[3][3], A3, B3);
  }

  // ---- epilogue: per-row max & sum(exp) over this tile's 128 cols; logits = acc/WSCALE ----
  // 16x16 C/D layout (verified m89): col = lane&15, row(within 16x16) = (lane>>4)*4 + r
  const float sc = 1.0f / WSCALE;
  float* sm_m = (float*)smA;             // [2][128]
  float* sm_s = (float*)(smA + 2048);    // [2][128]
  __syncthreads();                       // loop drained; safe to reuse LDS
#pragma unroll
  for (int i = 0; i < 4; ++i) {
#pragma unroll
    for (int r = 0; r < 4; ++r) {
      float l0 = acc[i][0][r] * sc, l1 = acc[i][1][r] * sc;
      float l2 = acc[i][2][r] * sc, l3 = acc[i][3][r] * sc;
      float m = fmaxf(fmaxf(l0, l1), fmaxf(l2, l3));
#pragma unroll
      for (int mk = 1; mk < 16; mk <<= 1) m = fmaxf(m, __shfl_xor(m, mk));
      float s = __expf(l0 - m) + __expf(l1 - m) + __expf(l2 - m) + __expf(l3 - m);
#pragma unroll
      for (int mk = 1; mk < 16; mk <<= 1) s += __shfl_xor(s, mk);
      if (li == 0) {
        int R = wr * 64 + i * 16 + lg * 4 + r;
        sm_m[wc * 128 + R] = m;
        sm_s[wc * 128 + R] = s;
      }
    }
  }
  __syncthreads();
  if (tid < BM) {
    float ma = sm_m[tid], mb = sm_m[128 + tid];
    float gm = fmaxf(ma, mb);
    float gs = sm_s[tid] * __expf(ma - gm) + sm_s[128 + tid] * __expf(mb - gm);
    long row = (long)(m0 + tid);
    pmax[row * NVT + vt] = gm;
    psum[row * NVT + vt] = gs;
  }
}

// ---------------- kernel 3: per-token LSE combine + exact fp32 target dot ----------------

__global__ void token_reduce(const float* __restrict__ x, const float* __restrict__ wgt,
                             const int* __restrict__ tgt,
                             const float* __restrict__ pmax, const float* __restrict__ psum,
                             float* __restrict__ nll, float* __restrict__ validf) {
  const int n = blockIdx.x;
  const int tid = threadIdx.x;
  const int lane = tid & 63;
  const int w = tid >> 6;
  __shared__ float smr[4];

  const int t = tgt[n];
  const bool valid = (t != IGNORE_INDEX);
  const int ts = valid ? t : 0;

  // exact fp32 target logit
  const float4* xr = (const float4*)(x + (long)n * DIM);
  const float4* wr = (const float4*)(wgt + (long)ts * DIM);
  float d = 0.f;
  for (int i = tid; i < DIM / 4; i += blockDim.x) {
    float4 a = xr[i], b = wr[i];
    d += a.x * b.x + a.y * b.y + a.z * b.z + a.w * b.w;
  }

  // LSE over 250 partials
  float m = (tid < NVT) ? pmax[(long)n * NVT + tid] : -INFINITY;
  float t1 = m;
#pragma unroll
  for (int mk = 1; mk < 64; mk <<= 1) t1 = fmaxf(t1, __shfl_xor(t1, mk));
  if (lane == 0) smr[w] = t1;
  __syncthreads();
  const float gm = fmaxf(fmaxf(smr[0], smr[1]), fmaxf(smr[2], smr[3]));
  __syncthreads();

  float se = (tid < NVT) ? psum[(long)n * NVT + tid] * __expf(m - gm) : 0.f;
#pragma unroll
  for (int mk = 1; mk < 64; mk <<= 1) se += __shfl_xor(se, mk);
  if (lane == 0) smr[w] = se;
  __syncthreads();
  const float gs = smr[0] + smr[1] + smr[2] + smr[3];
  __syncthreads();

#pragma unroll
  for (int mk = 1; mk < 64; mk <<= 1) d += __shfl_xor(d, mk);
  if (lane == 0) smr[w] = d;
  __syncthreads();
  const float gd = smr[0] + smr[1] + smr[2] + smr[3];

  if (tid == 0) {
    nll[n] = valid ? (gm + logf(gs) - gd) : 0.f;
    validf[n] = valid ? 1.f : 0.f;
  }
}

// ---------------- kernel 4: deterministic final mean ----------------

__global__ void final_reduce(const float* __restrict__ nll, const float* __restrict__ validf,
                             float* __restrict__ out, int n) {
  const int tid = threadIdx.x;
  const int lane = tid & 63;
  const int w = tid >> 6;
  __shared__ float sm1[4], sm2[4];
  float s = 0.f, c = 0.f;
  for (int i = tid; i < n; i += blockDim.x) { s += nll[i]; c += validf[i]; }
#pragma unroll
  for (int mk = 1; mk < 64; mk <<= 1) { s += __shfl_xor(s, mk); c += __shfl_xor(c, mk); }
  if (lane == 0) { sm1[w] = s; sm2[w] = c; }
  __syncthreads();
  if (tid == 0) {
    float ts = sm1[0] + sm1[1] + sm1[2] + sm1[3];
    float tc = sm2[0] + sm2[1] + sm2[2] + sm2[3];
    out[0] = ts / fmaxf(tc, 1.0f);
  }
}

// ---------------- launch ----------------

extern "C" void kernel_launch(void* const* d_in, const int* in_sizes, int n_in,
                              void* d_out, int out_size, void* d_ws, size_t ws_size,
                              hipStream_t stream) {
  const float* x = (const float*)d_in[0];     // [8192, 2048] fp32
  const float* wgt = (const float*)d_in[1];   // [32000, 2048] fp32
  const int* tgt = (const int*)d_in[2];       // [8192] int
  float* out = (float*)d_out;

  char* ws = (char*)d_ws;
  const size_t xq_off = 0;
  const size_t wq_off = (size_t)NTOK * DIM;                        // 16,777,216
  const size_t pm_off = wq_off + (size_t)VOC * DIM;                // 82,313,216
  const size_t ps_off = pm_off + (size_t)NTOK * NVT * 4;
  const size_t nl_off = ps_off + (size_t)NTOK * NVT * 4;
  const size_t vf_off = nl_off + (size_t)NTOK * 4;
  const size_t needed = vf_off + (size_t)NTOK * 4;
  if (ws_size < needed) return;  // workspace too small: fail visibly

  unsigned char* xq = (unsigned char*)(ws + xq_off);
  unsigned char* wq = (unsigned char*)(ws + wq_off);
  float* pmax = (float*)(ws + pm_off);
  float* psum = (float*)(ws + ps_off);
  float* nllv = (float*)(ws + nl_off);
  float* vldf = (float*)(ws + vf_off);

  cast_f32_fp8<<<2048, 256, 0, stream>>>(x, xq, (long)NTOK * DIM / 8, 1.0f);
  cast_f32_fp8<<<4096, 256, 0, stream>>>(wgt, wq, (long)VOC * DIM / 8, WSCALE);

  lce_gemm<<<NVT * MT, 256, 0, stream>>>(xq, wq, pmax, psum);

  token_reduce<<<NTOK, 256, 0, stream>>>(x, wgt, tgt, pmax, psum, nllv, vldf);
  final_reduce<<<1, 256, 0, stream>>>(nllv, vldf, out, NTOK);
}